// Round 14
// baseline (80.824 us; speedup 1.0000x reference)
//
#include <hip/hip_runtime.h>
#include <math.h>

#define HIDDEN 1024
#define NL 9
#define LEAN_TAU 0.25f
#define LEAN_DELTA 0.35f
#define LCH 16  // CRF scan chunk length

// v_add_f32 with DPP cross-lane source: full VALU rate, zero DS-pipe traffic.
template <int CTRL>
__device__ __forceinline__ float dppadd(float v) {
  const int s =
      __builtin_amdgcn_update_dpp(0, __float_as_int(v), CTRL, 0xf, 0xf, true);
  return v + __int_as_float(s);
}
// full-wave sum -> lane 63: row_shr 1,2,4,8 then row_bcast15, row_bcast31
__device__ __forceinline__ float wave_sum63(float v) {
  v = dppadd<0x111>(v);  // row_shr:1
  v = dppadd<0x112>(v);  // row_shr:2
  v = dppadd<0x114>(v);  // row_shr:4
  v = dppadd<0x118>(v);  // row_shr:8   -> lane15 of each row = row total
  v = dppadd<0x142>(v);  // row_bcast15 -> lane31 = rows0+1, lane63 = rows2+3
  v = dppadd<0x143>(v);  // row_bcast31 -> lane63 = all 64 lanes
  return v;
}

// ---------------- Kernel 1: emission logits + lean adjust ----------------
// R14: R8's LDS-weight GEMV but the 54 __shfl_xor/token (DS-pipe swizzles,
// ~6-deep dependent chain -- the cost shared by EVERY >=60us variant
// R5/R6/R8/R9/R12/R13) are replaced by DPP adds on the VALU. DS pipe keeps
// only 18 weight reads/token (TPW=2 shares each lw read across 2 tokens).
// Epilogue + 9 dword stores on lane 63. VGPR ~90, 36KB LDS -> 16 waves/CU.
__global__ __launch_bounds__(256) void logits_k(
    const float* __restrict__ hs, const float* __restrict__ w,
    const float* __restrict__ bias, const int* __restrict__ amask,
    float* __restrict__ e, int B, int T) {
  __shared__ float lw[NL * HIDDEN];
  const int TOK = T - 2;
  for (int i = threadIdx.x; i < NL * HIDDEN / 4; i += blockDim.x)
    reinterpret_cast<float4*>(lw)[i] = reinterpret_cast<const float4*>(w)[i];
  __syncthreads();
  const int wave = threadIdx.x >> 6, lane = threadIdx.x & 63;
  const int nTok = B * TOK;  // 64*510 = 32640 (even -> pairs never split)
  float bb[NL];
#pragma unroll
  for (int l = 0; l < NL; ++l) bb[l] = bias[l];

  const int nW2 = gridDim.x * 4 * 2;
  for (int base = (blockIdx.x * 4 + wave) * 2; base < nTok; base += nW2) {
    const int b0 = base / TOK, t0 = base - b0 * TOK;
    const int b1 = (base + 1) / TOK, t1 = (base + 1) - b1 * TOK;
    const float4* r0 =
        reinterpret_cast<const float4*>(hs + ((size_t)b0 * T + t0 + 1) * HIDDEN);
    const float4* r1 =
        reinterpret_cast<const float4*>(hs + ((size_t)b1 * T + t1 + 1) * HIDDEN);
    float4 hv0[4], hv1[4];
#pragma unroll
    for (int k = 0; k < 4; ++k) {
      hv0[k] = r0[lane + 64 * k];
      hv1[k] = r1[lane + 64 * k];
    }
    const int am0 = amask[b0 * T + t0 + 1];
    const int am1 = amask[b1 * T + t1 + 1];

    float acc0[NL], acc1[NL];
#pragma unroll
    for (int l = 0; l < NL; ++l) acc0[l] = acc1[l] = 0.f;
#pragma unroll
    for (int k = 0; k < 4; ++k) {
      const int h4 = lane + 64 * k;
#pragma unroll
      for (int l = 0; l < NL; ++l) {
        const float4 wv = reinterpret_cast<const float4*>(lw + l * HIDDEN)[h4];
        acc0[l] = fmaf(hv0[k].x, wv.x,
                  fmaf(hv0[k].y, wv.y,
                  fmaf(hv0[k].z, wv.z, fmaf(hv0[k].w, wv.w, acc0[l]))));
        acc1[l] = fmaf(hv1[k].x, wv.x,
                  fmaf(hv1[k].y, wv.y,
                  fmaf(hv1[k].z, wv.z, fmaf(hv1[k].w, wv.w, acc1[l]))));
      }
    }
    // VALU butterfly: full sums land in lane 63
#pragma unroll
    for (int l = 0; l < NL; ++l) {
      acc0[l] = wave_sum63(acc0[l]) + bb[l];
      acc1[l] = wave_sum63(acc1[l]) + bb[l];
    }
    // lane-63 epilogue (other lanes hold garbage; predicated stores)
    float m1 = -INFINITY, m2 = -INFINITY, n1 = -INFINITY, n2 = -INFINITY;
#pragma unroll
    for (int l = 0; l < NL; ++l) {
      const float v0 = acc0[l];
      if (v0 > m1) { m2 = m1; m1 = v0; }
      else if (v0 > m2) { m2 = v0; }
      const float v1 = acc1[l];
      if (v1 > n1) { n2 = n1; n1 = v1; }
      else if (v1 > n2) { n2 = v1; }
    }
    if ((m1 - m2 < LEAN_TAU) && (am0 != 0)) acc0[0] += LEAN_DELTA;
    if ((n1 - n2 < LEAN_TAU) && (am1 != 0)) acc1[0] += LEAN_DELTA;
    if (lane == 63) {
      float* d0 = e + (size_t)base * NL;
#pragma unroll
      for (int l = 0; l < NL; ++l) d0[l] = acc0[l];
      float* d1 = e + (size_t)(base + 1) * NL;
#pragma unroll
      for (int l = 0; l < NL; ++l) d1[l] = acc1[l];
    }
  }
}

// ---------------- Kernel 2: per-chunk log-space matrix products ----------------
// 7 chunks per wave; lane = sub*9 + i holds row i of chunk sub's 9x9 product.
// Factored logsumexp: W = exp(trans) in registers -> 9 exp + 9 log + 81 fma/step.
__global__ __launch_bounds__(64) void chunk_k(
    const float* __restrict__ e, const int* __restrict__ labels,
    const float* __restrict__ trans, float* __restrict__ Pout,
    int B, int T, int C) {
  const int TOK = T - 2;
  __shared__ float e2[7][LCH][NL];
  __shared__ float tr2[NL * NL];
  __shared__ int msk[7][LCH];
  const int tid = threadIdx.x;
  const int nG = B * C;
  const int gbase = blockIdx.x * 7;

  for (int idx = tid; idx < NL * NL; idx += 64) tr2[idx] = trans[idx];
  for (int idx = tid; idx < 7 * LCH * NL; idx += 64) {
    const int sub = idx / (LCH * NL), rem = idx % (LCH * NL);
    const int step = rem / NL, j = rem % NL;
    const int g = gbase + sub;
    if (g < nG) {
      const int b = g / C, c = g % C;
      const int t = 1 + c * LCH + step;
      if (t < TOK) e2[sub][step][j] = e[((size_t)b * TOK + t) * NL + j];
    }
  }
  for (int idx = tid; idx < 7 * LCH; idx += 64) {
    const int sub = idx / LCH, step = idx % LCH;
    const int g = gbase + sub;
    if (g < nG) {
      const int b = g / C, c = g % C;
      const int t = 1 + c * LCH + step;
      msk[sub][step] = (t < TOK) ? (labels[(size_t)b * T + 1 + t] != -100) : 0;
    }
  }
  __syncthreads();

  const int sub = tid / NL, i = tid % NL;  // sub==7 only for tid 63 (inactive)
  const int g = gbase + sub;
  const bool act = (sub < 7) && (g < nG);
  int len = 1;
  if (act) { const int c = g % C; len = min(LCH, TOK - (1 + c * LCH)); }

  float W[NL][NL];
#pragma unroll
  for (int k = 0; k < NL; ++k)
#pragma unroll
    for (int j = 0; j < NL; ++j) W[k][j] = __expf(tr2[k * NL + j]);

  float P[NL];
  {
    const int m0 = act ? msk[sub][0] : 0;
#pragma unroll
    for (int j = 0; j < NL; ++j)
      P[j] = m0 ? (tr2[i * NL + j] + e2[sub][0][j])
                : ((i == j) ? 0.f : -1e30f);
  }
  for (int step = 1; step < len; ++step) {
    const int mt = msk[sub][step];
    float mx = P[0];
#pragma unroll
    for (int k = 1; k < NL; ++k) mx = fmaxf(mx, P[k]);
    float E[NL];
#pragma unroll
    for (int k = 0; k < NL; ++k) E[k] = __expf(P[k] - mx);
    float Pn[NL];
#pragma unroll
    for (int j = 0; j < NL; ++j) {
      float s = 0.f;
#pragma unroll
      for (int k = 0; k < NL; ++k) s = fmaf(E[k], W[k][j], s);
      Pn[j] = mx + __logf(s) + e2[sub][step][j];
    }
#pragma unroll
    for (int j = 0; j < NL; ++j) P[j] = mt ? Pn[j] : P[j];
  }
  if (act) {
    float* dst = Pout + (size_t)g * 81 + i * NL;
#pragma unroll
    for (int j = 0; j < NL; ++j) dst[j] = P[j];
  }
}

// ---------------- Kernel 3: per-batch combine (num + den fold) ----------------
__global__ __launch_bounds__(64) void combine_k(
    const float* __restrict__ e, const int* __restrict__ labels,
    const float* __restrict__ start_t, const float* __restrict__ end_t,
    const float* __restrict__ trans, const float* __restrict__ Pmat,
    float* __restrict__ llh, int B, int T, int C) {
  const int TOK = T - 2;
  const int b = blockIdx.x, lane = threadIdx.x;
  const float* eb = e + (size_t)b * TOK * NL;
  const int* lb = labels + (size_t)b * T + 1;

  // ---- numerator: chain-free, data-parallel over t ----
  const int g0r = lb[0];
  const int tg0 = (g0r == -100) ? 0 : g0r;
  float nsum = 0.f;
  int pack = -1;  // (t<<4)|tag of last masked step
  for (int t = 1 + lane; t < TOK; t += 64) {
    const int gr = lb[t], pr = lb[t - 1];
    if (gr != -100) {
      const int cur = gr;
      const int prev = (pr == -100) ? 0 : pr;
      nsum += trans[prev * NL + cur] + eb[t * NL + cur];
      pack = (t << 4) | cur;
    }
  }
#pragma unroll
  for (int off = 32; off; off >>= 1) {
    nsum += __shfl_xor(nsum, off);
    pack = max(pack, __shfl_xor(pack, off));
  }
  const int last = (pack < 0) ? tg0 : (pack & 15);
  const float num = start_t[tg0] + eb[tg0] + nsum + end_t[last];

  // ---- denominator: fold C chunk matrices ----
  float alpha = (lane < NL) ? (start_t[lane] + eb[lane]) : -1e30f;
  for (int c = 0; c < C; ++c) {
    const float* Pc = Pmat + ((size_t)b * C + c) * 81;
    float col[NL];
#pragma unroll
    for (int i = 0; i < NL; ++i)
      col[i] = (lane < NL) ? Pc[i * NL + lane] : -1e30f;
    float s[NL];
    float mx = -1e30f;
#pragma unroll
    for (int i = 0; i < NL; ++i) {
      const float ai = __shfl(alpha, i);
      s[i] = ai + col[i];
      mx = fmaxf(mx, s[i]);
    }
    float sum = 0.f;
#pragma unroll
    for (int i = 0; i < NL; ++i) sum += __expf(s[i] - mx);
    const float nx = mx + __logf(sum);
    alpha = (lane < NL) ? nx : -1e30f;
  }
  const float v = (lane < NL) ? (alpha + end_t[lane]) : -1e30f;
  float mx = v;
#pragma unroll
  for (int off = 32; off; off >>= 1) mx = fmaxf(mx, __shfl_xor(mx, off));
  float sum = (lane < NL) ? __expf(v - mx) : 0.f;
#pragma unroll
  for (int off = 32; off; off >>= 1) sum += __shfl_xor(sum, off);
  const float den = mx + __logf(sum);
  if (lane == 0) llh[b] = num - den;
}

// ---------------- Kernel 4: -mean(llh) ----------------
__global__ __launch_bounds__(64) void reduce_k(const float* __restrict__ llh,
                                               float* __restrict__ out, int B) {
  float v = 0.f;
  for (int i = threadIdx.x; i < B; i += 64) v += llh[i];
#pragma unroll
  for (int off = 32; off; off >>= 1) v += __shfl_xor(v, off);
  if (threadIdx.x == 0) out[0] = -v / (float)B;
}

extern "C" void kernel_launch(void* const* d_in, const int* in_sizes, int n_in,
                              void* d_out, int out_size, void* d_ws,
                              size_t ws_size, hipStream_t stream) {
  const float* hs     = (const float*)d_in[0];
  const float* w      = (const float*)d_in[1];
  const float* bias   = (const float*)d_in[2];
  const float* st     = (const float*)d_in[3];
  const float* et     = (const float*)d_in[4];
  const float* tr     = (const float*)d_in[5];
  const int*   amask  = (const int*)d_in[6];
  const int*   labels = (const int*)d_in[7];

  const int T = 512;
  const int B = in_sizes[6] / T;
  const int TOK = T - 2;
  const int C = (TOK - 1 + LCH - 1) / LCH;  // chunks of the 509 recurrence steps

  float* e    = (float*)d_ws;                 // (B, TOK, 9)
  float* llh  = e + (size_t)B * TOK * NL;     // (B,)
  float* Pmat = llh + B;                      // (B*C, 81)

  logits_k<<<2048, 256, 0, stream>>>(hs, w, bias, amask, e, B, T);
  const int nG = B * C;
  chunk_k<<<(nG + 6) / 7, 64, 0, stream>>>(e, labels, tr, Pmat, B, T, C);
  combine_k<<<B, 64, 0, stream>>>(e, labels, st, et, tr, Pmat, llh, B, T, C);
  reduce_k<<<1, 64, 0, stream>>>(llh, (float*)d_out, B);
}